// Round 3
// baseline (1028.762 us; speedup 1.0000x reference)
//
#include <hip/hip_runtime.h>

#define T_DIM 2048
#define D_DIM 64
#define NHEAD 48
#define NTILE 128   // 16-row m-tiles per head

typedef _Float16 f16x8 __attribute__((ext_vector_type(8)));
typedef _Float16 f16x4 __attribute__((ext_vector_type(4)));
typedef float f32x4 __attribute__((ext_vector_type(4)));

__device__ inline f16x8 cvt8(f32x4 a, f32x4 b) {
    f16x8 r;
    r[0] = (_Float16)a[0]; r[1] = (_Float16)a[1];
    r[2] = (_Float16)a[2]; r[3] = (_Float16)a[3];
    r[4] = (_Float16)b[0]; r[5] = (_Float16)b[1];
    r[6] = (_Float16)b[2]; r[7] = (_Float16)b[3];
    return r;
}

// SINGLE-PASS causal softmax scores.
// One block (4 waves) owns ONE 16-row m-tile of one head. Each wave computes a
// strided subset of the causal k-tiles via swapped MFMA (A=K, B=Q: lane holds
// q-row li, 4 k-cols in acc regs), writes exp(s) as f16 into a 64 KB swizzled
// LDS row buffer, and accumulates per-row partial sums in registers.
// ONE barrier, then each wave normalizes 4 rows out of LDS and streams them to
// global with contiguous f32x4 stores. QK^T + exp run ONCE (prev: twice).
// fp32->fp16 input conversion is folded into the fragment loads (cvt kernels
// deleted). Blocks are XCD-pinned (head = (bid&7) + 8*grp -> per-XCD hot K set
// = 6 heads * 512 KB = 3 MB < 4 MB L2) and heavy/light tiles interleaved.
__global__ __launch_bounds__(256) void sdp_onepass(const float* __restrict__ qf,
                                                   const float* __restrict__ kf,
                                                   float* __restrict__ out) {
    __shared__ _Float16 ebuf[16 * T_DIM];   // 64 KB: [row][col] f16, XOR-swizzled
    __shared__ float sums[4][16];           // per-wave per-row partial sums

    const float scale = 0.125f;  // 64^-0.5

    // ---- block decode: XCD-pinned head, balanced tile order ----
    int bid  = blockIdx.x;          // 0..6143
    int xcd  = bid & 7;
    int t    = bid >> 3;            // 0..767
    int head = xcd + 8 * (t >> 7);  // 0..47, pinned to XCD = head%8
    int slot = t & 127;
    int mtg  = (slot & 1) ? (NTILE - 1 - (slot >> 1)) : (slot >> 1);  // 0,127,1,126,...

    int wave = threadIdx.x >> 6;
    int lane = threadIdx.x & 63;
    int g    = lane >> 4;   // k-col quad within tile / K-slice selector
    int li   = lane & 15;   // q-row within m-tile (also K-row for A loads)

    const float* qh = qf + (size_t)head * T_DIM * D_DIM;
    const float* kh = kf + (size_t)head * T_DIM * D_DIM;
    float* oh = out + (size_t)head * T_DIM * T_DIM;

    const int row0 = mtg * 16;     // first q-row of this tile
    const int NT   = mtg + 1;      // causal k-tiles (last one is the diagonal)
    const int zstart = NT * 16;    // first fully-masked column

    // ---- Q fragments (B operand), f32 -> f16 in-register ----
    f16x8 b_lo, b_hi;
    {
        const float* p = qh + (size_t)(row0 + li) * D_DIM + g * 8;
        b_lo = cvt8(*(const f32x4*)p,        *(const f32x4*)(p + 4));
        b_hi = cvt8(*(const f32x4*)(p + 32), *(const f32x4*)(p + 36));
    }

    // ---- single pass over this wave's k-tiles ----
    float psum = 0.f;
    const int swz = (li & 7) << 3;  // byte-XOR swizzle: spread rows across banks
#pragma unroll 2
    for (int kt = wave; kt < NT; kt += 4) {
        const float* p = kh + (size_t)(kt * 16 + li) * D_DIM + g * 8;
        f16x8 a_lo = cvt8(*(const f32x4*)p,        *(const f32x4*)(p + 4));
        f16x8 a_hi = cvt8(*(const f32x4*)(p + 32), *(const f32x4*)(p + 36));

        f32x4 acc = {0.f, 0.f, 0.f, 0.f};
        acc = __builtin_amdgcn_mfma_f32_16x16x32_f16(a_lo, b_lo, acc, 0, 0, 0);
        acc = __builtin_amdgcn_mfma_f32_16x16x32_f16(a_hi, b_hi, acc, 0, 0, 0);

        bool diag = (kt == NT - 1);       // wave-uniform
        int d = li - g * 4;               // causal: keep e <= d on the diagonal
        f16x4 ev;
#pragma unroll
        for (int e = 0; e < 4; ++e) {
            float ex = __expf(acc[e] * scale);
            if (diag && e > d) ex = 0.f;
            psum += ex;
            ev[e] = (_Float16)ex;
        }
        int cb = kt * 32 + g * 8;  // byte offset within row (8B granular)
        *(f16x4*)((char*)ebuf + li * 4096 + (cb ^ swz)) = ev;
    }

    // ---- zero tail: cols [zstart, T) for this wave's 4 rows (no LDS dep) ----
    {
        f32x4 z = {0.f, 0.f, 0.f, 0.f};
#pragma unroll
        for (int j = 0; j < 4; ++j) {
            float* rowp = oh + (size_t)(row0 + wave * 4 + j) * T_DIM;
            for (int c = zstart + lane * 4; c < T_DIM; c += 256)
                *(f32x4*)(rowp + c) = z;
        }
    }

    // ---- per-wave row sums -> LDS ----
    psum += __shfl_xor(psum, 16);
    psum += __shfl_xor(psum, 32);   // lanes li, li+16, li+32, li+48 now equal
    if (g == 0) sums[wave][li] = psum;

    __syncthreads();

    // ---- readout: normalize 4 rows per wave, contiguous f32x4 stores ----
    const int niter = (zstart + 255) >> 8;
#pragma unroll
    for (int j = 0; j < 4; ++j) {
        int r = wave * 4 + j;
        float rs = sums[0][r] + sums[1][r] + sums[2][r] + sums[3][r];
        float rinv = 1.0f / rs;
        float* rowp = oh + (size_t)(row0 + r) * T_DIM;
        int rsw = (r & 7) << 3;
        for (int i = 0; i < niter; ++i) {
            int col = i * 256 + lane * 4;
            if (col < zstart) {
                f16x4 ev = *(const f16x4*)((const char*)ebuf + r * 4096 + ((col * 2) ^ rsw));
                f32x4 o = { (float)ev[0] * rinv, (float)ev[1] * rinv,
                            (float)ev[2] * rinv, (float)ev[3] * rinv };
                *(f32x4*)(rowp + col) = o;
            }
        }
    }
}

extern "C" void kernel_launch(void* const* d_in, const int* in_sizes, int n_in,
                              void* d_out, int out_size, void* d_ws, size_t ws_size,
                              hipStream_t stream) {
    const float* q = (const float*)d_in[0];
    const float* k = (const float*)d_in[1];
    float* out = (float*)d_out;
    (void)d_ws; (void)ws_size;

    sdp_onepass<<<NHEAD * NTILE, 256, 0, stream>>>(q, k, out);
}